// Round 5
// baseline (217.793 us; speedup 1.0000x reference)
//
#include <hip/hip_runtime.h>

// SubjectConditionalLinear: y[b,n,o] = sum_h x[b,n,h] * W[sid[b],o,h] + bias[sid[b],o]
// x: [32,512,1024] f32, subject_id: [32] i32, weight: [8,1024,1024] f32, bias: [8,1024] f32
// out: [32,512,1024] f32
//
// R5: (1) x-conversion fused into GEMM: A-tile staged fp32 via global_load_lds
//     (XOR-swizzled), converted to bf16 in-register after fragment ds_reads.
//     (2) cvt kernel now weights-only (48 MB traffic vs 144).
//     (3) XCD swizzle: o-tile = g&7 -> per-XCD weight set = 2 MB, L2-resident.

constexpr int S_DIM = 8;
constexpr int O_DIM = 1024;
constexpr int H_DIM = 1024;
constexpr int B_DIM = 32;
constexpr int N_DIM = 512;

constexpr int BM = 128;
constexpr int BN = 128;
constexpr int BK = 64;
constexpr int NTHREADS = 256;

typedef short bf16x8 __attribute__((ext_vector_type(8)));
typedef float f32x4 __attribute__((ext_vector_type(4)));
typedef float f32x2 __attribute__((ext_vector_type(2)));
typedef __bf16 bf16x2 __attribute__((ext_vector_type(2)));

__device__ __forceinline__ unsigned int cvt_pk_bf16(float a, float b) {
  f32x2 v;
  v[0] = a;
  v[1] = b;
  bf16x2 r = __builtin_convertvector(v, bf16x2);  // v_cvt_pk_bf16_f32
  return __builtin_bit_cast(unsigned int, r);
}

__device__ __forceinline__ void gload_lds16(const void* g, void* l) {
  __builtin_amdgcn_global_load_lds(
      (const __attribute__((address_space(1))) unsigned int*)g,
      (__attribute__((address_space(3))) unsigned int*)l, 16, 0, 0);
}

// ---------- Phase 1: fp32 -> bf16 convert, WEIGHTS ONLY --------------------
__global__ __launch_bounds__(256) void cvt_kernel(
    const float* __restrict__ w, unsigned short* __restrict__ wb) {
  const long long base = (long long)blockIdx.x * 4096;
  const long long e0 = base + threadIdx.x * 4;
#pragma unroll
  for (int c = 0; c < 4; ++c) {
    const f32x4 v = __builtin_nontemporal_load((const f32x4*)(w + e0 + c * 1024));
    uint2 u;
    u.x = cvt_pk_bf16(v[0], v[1]);
    u.y = cvt_pk_bf16(v[2], v[3]);
    *(uint2*)(wb + e0 + c * 1024) = u;
  }
}

// ---------- Phase 2: GEMM. A staged fp32 (swizzled), B bf16 (swizzled) -----
__global__ __launch_bounds__(NTHREADS, 3) void scl_gemm(
    const float* __restrict__ x, const int* __restrict__ subject_id,
    const unsigned short* __restrict__ wb, const float* __restrict__ bias,
    float* __restrict__ out) {
  __shared__ __align__(16) float As[BM * BK];            // 32 KiB fp32
  __shared__ __align__(16) unsigned short Bs[BN * BK];   // 16 KiB bf16

  const int tid = threadIdx.x;
  // XCD swizzle: g&7 picks the o-tile -> one o-tile per XCD.
  const int g = blockIdx.x;
  const int o0 = (g & 7) * BN;
  const int t = g >> 3;          // 0..127
  const int b = t & 31;
  const int n0 = (t >> 5) * BM;  // 0..3 -> n-tile
  const int sid = subject_id[b];

  const int lane = tid & 63;
  const int wid = tid >> 6;
  const int wm0 = (wid >> 1) * 64;
  const int wn0 = (wid & 1) * 64;
  const int lcol = lane & 15;
  const int lq = lane >> 4;

  // --- A staging (fp32): wave covers rows wid*32..+32 = 8 KiB = 8 insts.
  // Inst i: 4 rows (lane>>4), 16 chunks of 16B (lane&15).
  // Swizzle: phys chunk p of row r holds logical chunk p ^ (r&7).
  const int arow_in_i = lane >> 4;                 // 0..3
  const int apc = lane & 15;                       // phys 16B chunk
  // --- B staging (bf16): as R4. Wave covers 32 rows = 4 KiB = 4 insts.
  const int brl = lane >> 3;                       // 0..7
  const int bpc = lane & 7;
  const int bsrow = wid * 32 + brl;
  const int bskc = (bpc ^ brl) * 8;
  const unsigned short* bg =
      wb + (size_t)(sid * O_DIM + o0 + bsrow) * H_DIM + bskc;
  float* as_wave = &As[(wid * 32) * BK];
  unsigned short* bs_wave = &Bs[(wid * 32) * BK];

  f32x4 acc[4][4];
#pragma unroll
  for (int mi = 0; mi < 4; ++mi)
#pragma unroll
    for (int ni = 0; ni < 4; ++ni) {
      f32x4 z = {0.f, 0.f, 0.f, 0.f};
      acc[mi][ni] = z;
    }

  for (int k0 = 0; k0 < H_DIM; k0 += BK) {
    __syncthreads();
#pragma unroll
    for (int i = 0; i < 8; ++i) {
      const int r = wid * 32 + i * 4 + arow_in_i;          // tile row
      const int lchunk = apc ^ (r & 7);                    // logical 16B chunk
      const float* ga =
          x + (size_t)(b * N_DIM + n0 + r) * H_DIM + k0 + lchunk * 4;
      gload_lds16(ga, as_wave + (size_t)(i * 4) * BK);     // dest: +lane*16 HW
    }
#pragma unroll
    for (int i = 0; i < 4; ++i) {
      gload_lds16(bg + (size_t)(i * 8) * H_DIM + k0, bs_wave + i * 8 * BK);
    }
    __syncthreads();

#pragma unroll
    for (int kk = 0; kk < BK; kk += 32) {
      const int kb = kk + lq * 8;       // first float of the 8-float A frag
      const int ac0 = kb >> 2;          // logical fp32 16B-chunk (even)
      const int bclog = (kk >> 3) + lq; // logical bf16 16B chunk
      bf16x8 af[4], bfr[4];
#pragma unroll
      for (int mi = 0; mi < 4; ++mi) {
        const int ar = wm0 + mi * 16 + lcol;
        const int sw = ar & 7;
        const f32x4 lo = *(const f32x4*)(&As[ar * BK + ((ac0 ^ sw) << 2)]);
        const f32x4 hi = *(const f32x4*)(&As[ar * BK + (((ac0 + 1) ^ sw) << 2)]);
        uint4 u;
        u.x = cvt_pk_bf16(lo[0], lo[1]);
        u.y = cvt_pk_bf16(lo[2], lo[3]);
        u.z = cvt_pk_bf16(hi[0], hi[1]);
        u.w = cvt_pk_bf16(hi[2], hi[3]);
        af[mi] = __builtin_bit_cast(bf16x8, u);
      }
#pragma unroll
      for (int ni = 0; ni < 4; ++ni) {
        const int br = wn0 + ni * 16 + lcol;
        bfr[ni] = *(const bf16x8*)(&Bs[br * BK + ((bclog ^ (br & 7)) << 3)]);
      }
#pragma unroll
      for (int mi = 0; mi < 4; ++mi)
#pragma unroll
        for (int ni = 0; ni < 4; ++ni)
          acc[mi][ni] = __builtin_amdgcn_mfma_f32_16x16x32_bf16(
              af[mi], bfr[ni], acc[mi][ni], 0, 0, 0);
    }
  }

  // Epilogue: C/D layout col = lane&15, row = (lane>>4)*4 + reg.
  float bv[4];
#pragma unroll
  for (int ni = 0; ni < 4; ++ni)
    bv[ni] = bias[sid * O_DIM + o0 + wn0 + ni * 16 + lcol];

  float* outb = out + (size_t)(b * N_DIM + n0 + wm0) * O_DIM + o0 + wn0 + lcol;
#pragma unroll
  for (int mi = 0; mi < 4; ++mi) {
#pragma unroll
    for (int r = 0; r < 4; ++r) {
      float* orow = outb + (size_t)(mi * 16 + lq * 4 + r) * O_DIM;
#pragma unroll
      for (int ni = 0; ni < 4; ++ni)
        orow[ni * 16] = acc[mi][ni][r] + bv[ni];
    }
  }
}

extern "C" void kernel_launch(void* const* d_in, const int* in_sizes, int n_in,
                              void* d_out, int out_size, void* d_ws, size_t ws_size,
                              hipStream_t stream) {
  const float* x = (const float*)d_in[0];
  const int* subject_id = (const int*)d_in[1];
  const float* weight = (const float*)d_in[2];
  const float* bias = (const float*)d_in[3];
  float* out = (float*)d_out;

  unsigned short* wb = (unsigned short*)d_ws;  // 16 MiB

  // weights: 8,388,608 floats / (256 thr * 16 elem) = 2048 blocks
  cvt_kernel<<<2048, 256, 0, stream>>>(weight, wb);

  scl_gemm<<<1024, NTHREADS, 0, stream>>>(x, subject_id, wb, bias, out);
}